// Round 2
// baseline (218.249 us; speedup 1.0000x reference)
//
#include <hip/hip_runtime.h>
#include <stdint.h>

#define HH 2048
#define WW 2048
#define NPIX (HH*WW)
#define MROW (WW/32)      // 64 mask words per row
#define TSX 64
#define TSY 32

// ---------------- Kernel A: fw u8 plane + bit-packed mask + init minmax ----------------
__global__ __launch_bounds__(256) void fw_kernel(
    const float* __restrict__ target, uint8_t* __restrict__ fw,
    uint32_t* __restrict__ mask, uint32_t* __restrict__ minmax)
{
    __shared__ uint8_t nib[256];
    const int t = threadIdx.x;
    const int i = blockIdx.x * 256 + t;   // quad index, grid sized exactly
    if (i == 0) { minmax[0] = 0x7F800000u; minmax[1] = 0u; }  // +inf, 0.0
    const float4* t4 = (const float4*)target;
    float4 a = t4[i];
    float4 b = t4[(NPIX/4) + i];
    float4 c = t4[2*(NPIX/4) + i];
    float4 d = t4[3*(NPIX/4) + i];
    float4 e = t4[4*(NPIX/4) + i];
    uchar4 o;
    o.x = (unsigned char)(a.x + b.x + c.x + d.x + e.x);
    o.y = (unsigned char)(a.y + b.y + c.y + d.y + e.y);
    o.z = (unsigned char)(a.z + b.z + c.z + d.z + e.z);
    o.w = (unsigned char)(a.w + b.w + c.w + d.w + e.w);
    ((uchar4*)fw)[i] = o;
    nib[t] = (uint8_t)((o.x ? 1u : 0u) | (o.y ? 2u : 0u) | (o.z ? 4u : 0u) | (o.w ? 8u : 0u));
    __syncthreads();
    if (t < 32) {
        const uint8_t* p = nib + t * 8;
        uint32_t w = 0;
        #pragma unroll
        for (int k = 0; k < 8; ++k) w |= (uint32_t)p[k] << (4 * k);
        mask[blockIdx.x * 32 + t] = w;   // 1024 consecutive pixels per block = 32 words
    }
}

// ---------------- Kernel B: contour + w = (fw+contour)^2, global min/max ----------------
// 64x32 tile per block, 256 threads (4 waves x 8 rows). Packed halo mask from global.
__global__ __launch_bounds__(256) void contour_kernel(
    const uint8_t* __restrict__ fw, const uint32_t* __restrict__ mask,
    const float* __restrict__ dk,
    float* __restrict__ wout, uint32_t* __restrict__ minmax)
{
    __shared__ uint32_t maskw[TSY + 8][4];  // halo rows x 128 bits (covers gx0-32 .. gx0+95)
    __shared__ float inv_d2[40];            // d^2 -> 1/dist

    const int t   = threadIdx.x;
    const int gx0 = blockIdx.x * TSX;
    const int gy0 = blockIdx.y * TSY;

    if (t < 81) {
        int iy = t / 9, jx = t - (t / 9) * 9;
        int dy = iy - 4, dx = jx - 4;
        int d2 = dy * dy + dx * dx;
        if (d2 != 0)
            inv_d2[d2] = 1.0f / (dk[t] / (1.0f + 1e-10f) + 1e-10f);
    }

    // halo mask: word wc covers bits gx0-32+32*wc; rows gy0-4 .. gy0+TSY+3 (clamped)
    const int w0 = gx0 >> 5;
    {
        int idx = t;                         // (TSY+8)*4 = 160 <= 256: one word per thread
        if (idx < (TSY + 8) * 4) {
            int hr = idx >> 2, wc = idx & 3;
            int gy = gy0 - 4 + hr; gy = min(max(gy, 0), HH - 1);
            const uint32_t* rowp = mask + gy * MROW;
            int wi = w0 - 1 + wc;
            uint32_t v;
            if (wi < 0)            v = (rowp[0] & 1u) ? 0xFFFFFFFFu : 0u;          // left edge clamp
            else if (wi > MROW-1)  v = (rowp[MROW-1] >> 31) ? 0xFFFFFFFFu : 0u;    // right edge clamp
            else                   v = rowp[wi];
            maskw[hr][wc] = v;
        }
    }
    __syncthreads();

    const int tx   = t & 63;       // tile column
    const int wid  = t >> 6;       // wave id: rows wid*8 .. wid*8+7
    const int r0   = wid * 8;
    const int pos  = tx + 28;      // bit position of gx-4 within the 128-bit row
    const int wsel = pos >> 5;
    const uint32_t sh = (uint32_t)(pos & 31);
    const int gx = gx0 + tx;

    // prefetch the 8 fw bytes (independent loads, overlap latency)
    float fwv[8];
    #pragma unroll
    for (int r = 0; r < 8; ++r)
        fwv[r] = (float)fw[(gy0 + r0 + r) * WW + gx];

    // rolling 9-row window of 9-bit mask slices (bit k = dx offset k-4)
    uint32_t w9[9];
    #pragma unroll
    for (int k = 0; k < 9; ++k) {
        uint32_t lo = maskw[r0 + k][wsel];
        uint32_t hi = maskw[r0 + k][wsel + 1];
        w9[k] = (uint32_t)(((((uint64_t)hi) << 32) | lo) >> sh) & 0x1FFu;
    }

    float lmn = __int_as_float(0x7F800000);  // +inf
    float lmx = 0.0f;

    #pragma unroll
    for (int r = 0; r < 8; ++r) {
        uint32_t cbit = (w9[4] >> 4) & 1u;
        uint32_t cm = 0u - cbit;
        uint32_t mind2 = 999u;
        #pragma unroll
        for (int dy = 0; dy < 9; ++dy) {
            uint32_t x = (w9[dy] ^ cm) & 0x1FFu;              // differ bits
            uint32_t rev = __builtin_bitreverse32(x) >> 23;   // 9-bit reverse: dx -> -dx
            uint32_t g = (((x | rev) >> 4) & 0x1Fu) | 0x100u; // bit k = |dx|==k; sentinel
            uint32_t mk = (uint32_t)__builtin_ctz(g);
            uint32_t d2 = mk * mk + (uint32_t)((dy - 4) * (dy - 4));
            mind2 = min(mind2, d2);
        }
        float contour = (mind2 <= 32u) ? inv_d2[mind2] : 0.0f;
        float wv = fwv[r] + contour;
        wv = wv * wv;
        wout[(gy0 + r0 + r) * WW + gx] = wv;
        lmn = fminf(lmn, wv);
        lmx = fmaxf(lmx, wv);
        if (r < 7) {
            #pragma unroll
            for (int k = 0; k < 8; ++k) w9[k] = w9[k + 1];
            uint32_t lo = maskw[r0 + r + 9][wsel];
            uint32_t hi = maskw[r0 + r + 9][wsel + 1];
            w9[8] = (uint32_t)(((((uint64_t)hi) << 32) | lo) >> sh) & 0x1FFu;
        }
    }

    // wave reduce min/max, one atomic pair per wave (uint order valid for nonneg floats)
    #pragma unroll
    for (int off = 32; off > 0; off >>= 1) {
        lmn = fminf(lmn, __shfl_xor(lmn, off));
        lmx = fmaxf(lmx, __shfl_xor(lmx, off));
    }
    if (tx == 0) {
        atomicMin(minmax + 0, __float_as_uint(lmn));
        atomicMax(minmax + 1, __float_as_uint(lmx));
    }
}

// ---------------- Kernel C: normalize + mask ----------------
__global__ __launch_bounds__(256) void norm_kernel(
    const float* w, const uint32_t* __restrict__ mask,
    const uint32_t* __restrict__ minmax, float* out)
{
    int i = blockIdx.x * 256 + threadIdx.x;   // quad index, grid sized exactly
    float mn = __uint_as_float(minmax[0]);
    float mx = __uint_as_float(minmax[1]);
    float rden = 1.0f / (mx - mn + 1e-10f);
    float4 wv = ((const float4*)w)[i];
    uint32_t nibw = mask[i >> 3];
    uint32_t nib = (nibw >> ((i & 7) * 4)) & 0xFu;
    float4 o;
    o.x = (nib & 1u) ? (wv.x - mn) * rden : 0.0f;
    o.y = (nib & 2u) ? (wv.y - mn) * rden : 0.0f;
    o.z = (nib & 4u) ? (wv.z - mn) * rden : 0.0f;
    o.w = (nib & 8u) ? (wv.w - mn) * rden : 0.0f;
    ((float4*)out)[i] = o;
}

extern "C" void kernel_launch(void* const* d_in, const int* in_sizes, int n_in,
                              void* d_out, int out_size, void* d_ws, size_t ws_size,
                              hipStream_t stream)
{
    const float* target = (const float*)d_in[0];
    const float* dk     = (const float*)d_in[1];
    float* out = (float*)d_out;

    uint8_t* wsb = (uint8_t*)d_ws;
    uint32_t* minmax = (uint32_t*)wsb;                 // 2 x u32
    uint8_t*  fw     = wsb + 256;                      // 4 MB u8 plane
    uint32_t* mask   = (uint32_t*)(wsb + 256 + NPIX);  // 512 KB packed combined-mask

    fw_kernel<<<NPIX / 4 / 256, 256, 0, stream>>>(target, fw, mask, minmax);

    dim3 gridB(WW / TSX, HH / TSY);
    contour_kernel<<<gridB, 256, 0, stream>>>(fw, mask, dk, out, minmax);

    norm_kernel<<<NPIX / 4 / 256, 256, 0, stream>>>(out, mask, minmax, out);
}

// Round 3
// 42.314 us; speedup vs baseline: 5.1578x; 5.1578x over previous
//
#include <hip/hip_runtime.h>
#include <stdint.h>

#define HH 2048
#define WW 2048
#define NPIX (HH*WW)
#define MROW (WW/32)      // 64 mask words per row
#define TSX 64
#define TSY 32
#define NBLK ((WW/TSX)*(HH/TSY))   // 2048 contour blocks

// ---------------- Kernel A: fw u8 plane + bit-packed mask ----------------
__global__ __launch_bounds__(256) void fw_kernel(
    const float* __restrict__ target, uint8_t* __restrict__ fw,
    uint32_t* __restrict__ mask)
{
    __shared__ uint8_t nib[256];
    const int t = threadIdx.x;
    const int i = blockIdx.x * 256 + t;   // quad index, grid sized exactly
    const float4* t4 = (const float4*)target;
    float4 a = t4[i];
    float4 b = t4[(NPIX/4) + i];
    float4 c = t4[2*(NPIX/4) + i];
    float4 d = t4[3*(NPIX/4) + i];
    float4 e = t4[4*(NPIX/4) + i];
    uchar4 o;
    o.x = (unsigned char)(a.x + b.x + c.x + d.x + e.x);
    o.y = (unsigned char)(a.y + b.y + c.y + d.y + e.y);
    o.z = (unsigned char)(a.z + b.z + c.z + d.z + e.z);
    o.w = (unsigned char)(a.w + b.w + c.w + d.w + e.w);
    ((uchar4*)fw)[i] = o;
    nib[t] = (uint8_t)((o.x ? 1u : 0u) | (o.y ? 2u : 0u) | (o.z ? 4u : 0u) | (o.w ? 8u : 0u));
    __syncthreads();
    if (t < 32) {
        const uint8_t* p = nib + t * 8;
        uint32_t w = 0;
        #pragma unroll
        for (int k = 0; k < 8; ++k) w |= (uint32_t)p[k] << (4 * k);
        mask[blockIdx.x * 32 + t] = w;   // 1024 consecutive pixels per block = 32 words
    }
}

// ---------------- Kernel B: contour + w = (fw+contour)^2, per-block min/max ----------------
// 64x32 tile per block, 256 threads (4 waves x 8 rows). Packed halo mask from global.
__global__ __launch_bounds__(256) void contour_kernel(
    const uint8_t* __restrict__ fw, const uint32_t* __restrict__ mask,
    const float* __restrict__ dk,
    float* __restrict__ wout, float* __restrict__ pmin, float* __restrict__ pmax)
{
    __shared__ uint32_t maskw[TSY + 8][4];  // halo rows x 128 bits (covers gx0-32 .. gx0+95)
    __shared__ float inv_d2[40];            // d^2 -> 1/dist
    __shared__ float redmn[4], redmx[4];

    const int t   = threadIdx.x;
    const int gx0 = blockIdx.x * TSX;
    const int gy0 = blockIdx.y * TSY;

    if (t < 81) {
        int iy = t / 9, jx = t - (t / 9) * 9;
        int dy = iy - 4, dx = jx - 4;
        int d2 = dy * dy + dx * dx;
        if (d2 != 0)
            inv_d2[d2] = 1.0f / (dk[t] / (1.0f + 1e-10f) + 1e-10f);
    }

    // halo mask: word wc covers bits gx0-32+32*wc; rows gy0-4 .. gy0+TSY+3 (clamped)
    const int w0 = gx0 >> 5;
    if (t < (TSY + 8) * 4) {                 // 160 <= 256: one word per thread
        int hr = t >> 2, wc = t & 3;
        int gy = gy0 - 4 + hr; gy = min(max(gy, 0), HH - 1);
        const uint32_t* rowp = mask + gy * MROW;
        int wi = w0 - 1 + wc;
        uint32_t v;
        if (wi < 0)            v = (rowp[0] & 1u) ? 0xFFFFFFFFu : 0u;          // left edge clamp
        else if (wi > MROW-1)  v = (rowp[MROW-1] >> 31) ? 0xFFFFFFFFu : 0u;    // right edge clamp
        else                   v = rowp[wi];
        maskw[hr][wc] = v;
    }
    __syncthreads();

    const int tx   = t & 63;       // tile column
    const int wid  = t >> 6;       // wave id: rows wid*8 .. wid*8+7
    const int r0   = wid * 8;
    const int pos  = tx + 28;      // bit position of gx-4 within the 128-bit row
    const int wsel = pos >> 5;
    const uint32_t sh = (uint32_t)(pos & 31);
    const int gx = gx0 + tx;

    // prefetch the 8 fw bytes (independent loads, overlap latency)
    float fwv[8];
    #pragma unroll
    for (int r = 0; r < 8; ++r)
        fwv[r] = (float)fw[(gy0 + r0 + r) * WW + gx];

    // rolling 9-row window of 9-bit mask slices (bit k = dx offset k-4)
    uint32_t w9[9];
    #pragma unroll
    for (int k = 0; k < 9; ++k) {
        uint32_t lo = maskw[r0 + k][wsel];
        uint32_t hi = maskw[r0 + k][wsel + 1];
        w9[k] = (uint32_t)(((((uint64_t)hi) << 32) | lo) >> sh) & 0x1FFu;
    }

    float lmn = __int_as_float(0x7F800000);  // +inf
    float lmx = 0.0f;

    #pragma unroll
    for (int r = 0; r < 8; ++r) {
        uint32_t cbit = (w9[4] >> 4) & 1u;
        uint32_t cm = 0u - cbit;
        uint32_t mind2 = 999u;
        #pragma unroll
        for (int dy = 0; dy < 9; ++dy) {
            uint32_t x = (w9[dy] ^ cm) & 0x1FFu;              // differ bits
            uint32_t rev = __builtin_bitreverse32(x) >> 23;   // 9-bit reverse: dx -> -dx
            uint32_t g = (((x | rev) >> 4) & 0x1Fu) | 0x100u; // bit k = |dx|==k; sentinel
            uint32_t mk = (uint32_t)__builtin_ctz(g);
            uint32_t d2 = mk * mk + (uint32_t)((dy - 4) * (dy - 4));
            mind2 = min(mind2, d2);
        }
        float contour = (mind2 <= 32u) ? inv_d2[mind2] : 0.0f;
        float wv = fwv[r] + contour;
        wv = wv * wv;
        wout[(gy0 + r0 + r) * WW + gx] = wv;
        lmn = fminf(lmn, wv);
        lmx = fmaxf(lmx, wv);
        if (r < 7) {
            #pragma unroll
            for (int k = 0; k < 8; ++k) w9[k] = w9[k + 1];
            uint32_t lo = maskw[r0 + r + 9][wsel];
            uint32_t hi = maskw[r0 + r + 9][wsel + 1];
            w9[8] = (uint32_t)(((((uint64_t)hi) << 32) | lo) >> sh) & 0x1FFu;
        }
    }

    // wave reduce min/max, then LDS reduce across 4 waves, ONE pair of plain
    // stores per block (same-address atomics were the round-2 bottleneck:
    // 16384 same-line atomics x ~12ns serialization = 190us)
    #pragma unroll
    for (int off = 32; off > 0; off >>= 1) {
        lmn = fminf(lmn, __shfl_xor(lmn, off));
        lmx = fmaxf(lmx, __shfl_xor(lmx, off));
    }
    if (tx == 0) { redmn[wid] = lmn; redmx[wid] = lmx; }
    __syncthreads();
    if (t == 0) {
        float mn = fminf(fminf(redmn[0], redmn[1]), fminf(redmn[2], redmn[3]));
        float mx = fmaxf(fmaxf(redmx[0], redmx[1]), fmaxf(redmx[2], redmx[3]));
        int bid = blockIdx.y * gridDim.x + blockIdx.x;
        pmin[bid] = mn;
        pmax[bid] = mx;
    }
}

// ---------------- Kernel R: reduce 2048 partials -> minmax[2] ----------------
__global__ __launch_bounds__(1024) void reduce_kernel(
    const float* __restrict__ pmin, const float* __restrict__ pmax,
    float* __restrict__ minmax)
{
    __shared__ float smn[16], smx[16];
    const int t = threadIdx.x;
    float mn = fminf(pmin[t], pmin[t + 1024]);
    float mx = fmaxf(pmax[t], pmax[t + 1024]);
    #pragma unroll
    for (int off = 32; off > 0; off >>= 1) {
        mn = fminf(mn, __shfl_xor(mn, off));
        mx = fmaxf(mx, __shfl_xor(mx, off));
    }
    const int w = t >> 6;
    if ((t & 63) == 0) { smn[w] = mn; smx[w] = mx; }
    __syncthreads();
    if (t < 16) {
        mn = smn[t]; mx = smx[t];
        #pragma unroll
        for (int off = 8; off > 0; off >>= 1) {
            mn = fminf(mn, __shfl_xor(mn, off));
            mx = fmaxf(mx, __shfl_xor(mx, off));
        }
        if (t == 0) { minmax[0] = mn; minmax[1] = mx; }
    }
}

// ---------------- Kernel C: normalize + mask ----------------
__global__ __launch_bounds__(256) void norm_kernel(
    const float* w, const uint32_t* __restrict__ mask,
    const float* __restrict__ minmax, float* out)
{
    int i = blockIdx.x * 256 + threadIdx.x;   // quad index, grid sized exactly
    float mn = minmax[0];
    float mx = minmax[1];
    float rden = 1.0f / (mx - mn + 1e-10f);
    float4 wv = ((const float4*)w)[i];
    uint32_t nibw = mask[i >> 3];
    uint32_t nib = (nibw >> ((i & 7) * 4)) & 0xFu;
    float4 o;
    o.x = (nib & 1u) ? (wv.x - mn) * rden : 0.0f;
    o.y = (nib & 2u) ? (wv.y - mn) * rden : 0.0f;
    o.z = (nib & 4u) ? (wv.z - mn) * rden : 0.0f;
    o.w = (nib & 8u) ? (wv.w - mn) * rden : 0.0f;
    ((float4*)out)[i] = o;
}

extern "C" void kernel_launch(void* const* d_in, const int* in_sizes, int n_in,
                              void* d_out, int out_size, void* d_ws, size_t ws_size,
                              hipStream_t stream)
{
    const float* target = (const float*)d_in[0];
    const float* dk     = (const float*)d_in[1];
    float* out = (float*)d_out;

    uint8_t* wsb = (uint8_t*)d_ws;
    float*    minmax = (float*)wsb;                          // 2 x f32
    uint8_t*  fw     = wsb + 256;                            // 4 MB u8 plane
    uint32_t* mask   = (uint32_t*)(wsb + 256 + NPIX);        // 512 KB packed mask
    float*    pmin   = (float*)(wsb + 256 + NPIX + NPIX/8);  // 8 KB partial mins
    float*    pmax   = pmin + NBLK;                          // 8 KB partial maxs

    fw_kernel<<<NPIX / 4 / 256, 256, 0, stream>>>(target, fw, mask);

    dim3 gridB(WW / TSX, HH / TSY);
    contour_kernel<<<gridB, 256, 0, stream>>>(fw, mask, dk, out, pmin, pmax);

    reduce_kernel<<<1, 1024, 0, stream>>>(pmin, pmax, minmax);

    norm_kernel<<<NPIX / 4 / 256, 256, 0, stream>>>(out, mask, minmax, out);
}